// Round 1
// baseline (93.897 us; speedup 1.0000x reference)
//
#include <hip/hip_runtime.h>

#define BATCH 256
#define IN1   10240
#define NU    32
#define NB    32               // batches per block in kernel1
#define BGROUPS (BATCH / NB)   // 8
#define LOG2E 1.4426950408889634f

// Kernel 1: partial sensory-synapse sums over an i-stripe.
// thread = (i_local = tid>>5 in 0..7, u = tid&31); NB batches accumulated in regs.
// sigmoid((x*iw+ib - smu)*ssig) = rcp(1 + exp2(C - x*A)),
//   A = iw*ssig*log2e, C = (smu - ib)*ssig*log2e
__global__ __launch_bounds__(256) void ltc_sensory_partial(
    const float* __restrict__ x,
    const float* __restrict__ iw, const float* __restrict__ ibias,
    const float* __restrict__ smu, const float* __restrict__ ssig,
    const float* __restrict__ sW, const float* __restrict__ serev,
    float* __restrict__ pnum, float* __restrict__ pden,
    int stripe)
{
    const int tid = threadIdx.x;
    const int u   = tid & 31;
    const int il  = tid >> 5;          // 0..7
    const int w   = tid >> 6;          // wave 0..3
    const int bg  = blockIdx.x;        // 0..BGROUPS-1
    const int is  = blockIdx.y;        // i-split index
    const int b0  = bg * NB;
    const int ibase = is * stripe;
    const int iend  = (ibase + stripe < IN1) ? (ibase + stripe) : IN1;

    float accn[NB], accd[NB];
#pragma unroll
    for (int n = 0; n < NB; ++n) { accn[n] = 0.f; accd[n] = 0.f; }

    for (int i = ibase + il; i < iend; i += 8) {
        const int pi = i * NU + u;
        float A = ssig[pi] * LOG2E;
        const float C = (smu[pi] - ibias[i]) * A;
        A *= iw[i];
        const float sw  = sW[pi];
        const float swe = sw * serev[pi];
        const float* xp = x + i;
#pragma unroll
        for (int n = 0; n < NB; ++n) {
            const float xv = xp[(size_t)(b0 + n) * IN1];
            const float e  = __builtin_amdgcn_exp2f(C - xv * A);
            const float r  = __builtin_amdgcn_rcpf(1.0f + e);
            accd[n] = fmaf(sw,  r, accd[n]);
            accn[n] = fmaf(swe, r, accn[n]);
        }
    }

    // deterministic reduction over i_local (8 threads spread across 4 waves)
    __shared__ float wred[4][NB][NU][2];   // 32 KB
#pragma unroll
    for (int n = 0; n < NB; ++n) {
        float vn = accn[n] + __shfl_xor(accn[n], 32, 64);
        float vd = accd[n] + __shfl_xor(accd[n], 32, 64);
        if ((tid & 63) < 32) {
            wred[w][n][u][0] = vn;
            wred[w][n][u][1] = vd;
        }
    }
    __syncthreads();
    for (int p = tid; p < NB * NU; p += 256) {
        const int n = p >> 5, uu = p & 31;
        const float sn = wred[0][n][uu][0] + wred[1][n][uu][0]
                       + wred[2][n][uu][0] + wred[3][n][uu][0];
        const float sd = wred[0][n][uu][1] + wred[1][n][uu][1]
                       + wred[2][n][uu][1] + wred[3][n][uu][1];
        const size_t gi = ((size_t)is * BATCH + (b0 + n)) * NU + uu;
        pnum[gi] = sn;
        pden[gi] = sd;
    }
}

// Kernel 2: reduce partials, 6 LTC unfolds for cell A (32 units, shfl-broadcast
// presynaptic v), then cell B (32 -> 1) and final sigmoid.
__global__ __launch_bounds__(256) void ltc_unfold(
    const float* __restrict__ pnum, const float* __restrict__ pden, int nsplit,
    const float* __restrict__ amu, const float* __restrict__ asig,
    const float* __restrict__ aW,  const float* __restrict__ aerev,
    const float* __restrict__ agleak, const float* __restrict__ avleak,
    const float* __restrict__ acm,
    const float* __restrict__ b_iw, const float* __restrict__ b_ib,
    const float* __restrict__ b_smu, const float* __restrict__ b_ssig,
    const float* __restrict__ b_sW,  const float* __restrict__ b_serev,
    const float* __restrict__ b_mu,  const float* __restrict__ b_sig,
    const float* __restrict__ b_W,   const float* __restrict__ b_erev,
    const float* __restrict__ b_gleak, const float* __restrict__ b_vleak,
    const float* __restrict__ b_cm,
    float* __restrict__ out)
{
    const int tid = threadIdx.x;
    const int u  = tid & 31;
    const int bl = tid >> 5;                 // 0..7
    const int b  = blockIdx.x * 8 + bl;      // 0..255

    float Sn = 0.f, Sd = 0.f;
    for (int s = 0; s < nsplit; ++s) {
        const size_t gi = ((size_t)s * BATCH + b) * NU + u;
        Sn += pnum[gi];
        Sd += pden[gi];
    }

    const float cmt = acm[u] * 6.0f;         // cm / (ELAPSED/UNFOLDS)
    const float gl  = agleak[u];
    const float gv  = gl * avleak[u];

    float v = 0.f;
    for (int k = 0; k < 6; ++k) {
        float rn = 0.f, rd = 0.f;
#pragma unroll 8
        for (int j = 0; j < NU; ++j) {
            const float vj = __shfl(v, j, 32);          // presynaptic v[b][j]
            const int pi = j * NU + u;
            const float e = __builtin_amdgcn_exp2f((amu[pi] - vj) * asig[pi] * LOG2E);
            const float s = aW[pi] * __builtin_amdgcn_rcpf(1.0f + e);
            rn = fmaf(s, aerev[pi], rn);
            rd += s;
        }
        const float num = cmt * v + gv + rn + Sn;
        const float den = cmt + gl + rd + Sd;
        v = num / den;
    }

    // ---- cell B: n_in = 32, n_u = 1 ----
    const float x2 = v * b_iw[u] + b_ib[u];
    const float e2 = __builtin_amdgcn_exp2f((b_smu[u] - x2) * b_ssig[u] * LOG2E);
    const float s2 = b_sW[u] * __builtin_amdgcn_rcpf(1.0f + e2);
    float wn = s2 * b_serev[u];
    float wd = s2;
#pragma unroll
    for (int m = 16; m >= 1; m >>= 1) {
        wn += __shfl_xor(wn, m, 32);
        wd += __shfl_xor(wd, m, 32);
    }

    const float bcmt = b_cm[0] * 6.0f;
    const float bgl  = b_gleak[0];
    const float bgv  = bgl * b_vleak[0];
    const float bmu  = b_mu[0], bsig = b_sig[0], bW = b_W[0], berev = b_erev[0];
    float v2 = 0.f;
#pragma unroll
    for (int k = 0; k < 6; ++k) {
        const float ee = __builtin_amdgcn_exp2f((bmu - v2) * bsig * LOG2E);
        const float ws = bW * __builtin_amdgcn_rcpf(1.0f + ee);
        const float num = bcmt * v2 + bgv + ws * berev + wn;
        const float den = bcmt + bgl + ws + wd;
        v2 = num / den;
    }

    if (u == 0)
        out[b] = 1.0f / (1.0f + __builtin_amdgcn_exp2f(-v2 * LOG2E));
}

extern "C" void kernel_launch(void* const* d_in, const int* in_sizes, int n_in,
                              void* d_out, int out_size, void* d_ws, size_t ws_size,
                              hipStream_t stream) {
    const float* x       = (const float*)d_in[0];
    const float* a_iw    = (const float*)d_in[1];
    const float* a_ib    = (const float*)d_in[2];
    const float* a_smu   = (const float*)d_in[3];
    const float* a_ssig  = (const float*)d_in[4];
    const float* a_sW    = (const float*)d_in[5];
    const float* a_serev = (const float*)d_in[6];
    const float* a_mu    = (const float*)d_in[7];
    const float* a_sig   = (const float*)d_in[8];
    const float* a_W     = (const float*)d_in[9];
    const float* a_erev  = (const float*)d_in[10];
    const float* a_gleak = (const float*)d_in[11];
    const float* a_vleak = (const float*)d_in[12];
    const float* a_cm    = (const float*)d_in[13];
    const float* b_iw    = (const float*)d_in[14];
    const float* b_ib    = (const float*)d_in[15];
    const float* b_smu   = (const float*)d_in[16];
    const float* b_ssig  = (const float*)d_in[17];
    const float* b_sW    = (const float*)d_in[18];
    const float* b_serev = (const float*)d_in[19];
    const float* b_mu    = (const float*)d_in[20];
    const float* b_sig   = (const float*)d_in[21];
    const float* b_W     = (const float*)d_in[22];
    const float* b_erev  = (const float*)d_in[23];
    const float* b_gleak = (const float*)d_in[24];
    const float* b_vleak = (const float*)d_in[25];
    const float* b_cm    = (const float*)d_in[26];
    float* out = (float*)d_out;

    // choose i-splits to fit workspace: 2 arrays of [splits][256][32] f32
    int splits = 128;
    while (splits > 1 &&
           (size_t)splits * BATCH * NU * 2 * sizeof(float) > ws_size)
        splits >>= 1;
    int stripe = (IN1 + splits - 1) / splits;
    stripe = (stripe + 7) & ~7;                      // multiple of 8 (i_local)
    const int gy = (IN1 + stripe - 1) / stripe;      // actual splits used

    float* pnum = (float*)d_ws;
    float* pden = pnum + (size_t)splits * BATCH * NU;

    dim3 grid1(BGROUPS, gy);
    ltc_sensory_partial<<<grid1, 256, 0, stream>>>(
        x, a_iw, a_ib, a_smu, a_ssig, a_sW, a_serev, pnum, pden, stripe);

    ltc_unfold<<<BATCH / 8, 256, 0, stream>>>(
        pnum, pden, gy,
        a_mu, a_sig, a_W, a_erev, a_gleak, a_vleak, a_cm,
        b_iw, b_ib, b_smu, b_ssig, b_sW, b_serev,
        b_mu, b_sig, b_W, b_erev, b_gleak, b_vleak, b_cm,
        out);
}

// Round 2
// 50.674 us; speedup vs baseline: 1.8529x; 1.8529x over previous
//
#include <hip/hip_runtime.h>

#define BATCH 256
#define IN1   10240
#define NU    32
#define NB    32
#define BGROUPS (BATCH / NB)
#define LOG2E 1.4426950408889634f

__global__ __launch_bounds__(256) void ltc_sensory_partial(
    const float* __restrict__ x,
    const float* __restrict__ iw, const float* __restrict__ ibias,
    const float* __restrict__ smu, const float* __restrict__ ssig,
    const float* __restrict__ sW, const float* __restrict__ serev,
    float* __restrict__ pnum, float* __restrict__ pden,
    int stripe)
{
    const int tid = threadIdx.x;
    const int u   = tid & 31;
    const int il  = tid >> 5;
    const int w   = tid >> 6;
    const int bg  = blockIdx.x;
    const int is  = blockIdx.y;
    const int b0  = bg * NB;
    const int ibase = is * stripe;
    const int iend  = (ibase + stripe < IN1) ? (ibase + stripe) : IN1;

    float accn[NB], accd[NB];
#pragma unroll
    for (int n = 0; n < NB; ++n) { accn[n] = 0.f; accd[n] = 0.f; }

    for (int i = ibase + il; i < iend; i += 8) {
        const int pi = i * NU + u;
        float A = ssig[pi] * LOG2E;
        const float C = (smu[pi] - ibias[i]) * A;
        A *= iw[i];
        const float sw  = sW[pi];
        const float swe = sw * serev[pi];
        const float* xp = x + i;
#pragma unroll
        for (int n = 0; n < NB; ++n) {
            const float xv = xp[(size_t)(b0 + n) * IN1];
            const float e  = __builtin_amdgcn_exp2f(C - xv * A);
            const float r  = __builtin_amdgcn_rcpf(1.0f + e);
            accd[n] = fmaf(sw,  r, accd[n]);
            accn[n] = fmaf(swe, r, accn[n]);
        }
    }

    __shared__ float wred[4][NB][NU][2];
#pragma unroll
    for (int n = 0; n < NB; ++n) {
        float vn = accn[n] + __shfl_xor(accn[n], 32, 64);
        float vd = accd[n] + __shfl_xor(accd[n], 32, 64);
        if ((tid & 63) < 32) {
            wred[w][n][u][0] = vn;
            wred[w][n][u][1] = vd;
        }
    }
    __syncthreads();
    for (int p = tid; p < NB * NU; p += 256) {
        const int n = p >> 5, uu = p & 31;
        const float sn = wred[0][n][uu][0] + wred[1][n][uu][0]
                       + wred[2][n][uu][0] + wred[3][n][uu][0];
        const float sd = wred[0][n][uu][1] + wred[1][n][uu][1]
                       + wred[2][n][uu][1] + wred[3][n][uu][1];
        const size_t gi = ((size_t)is * BATCH + (b0 + n)) * NU + uu;
        pnum[gi] = sn;
        pden[gi] = sd;
    }
}

// Kernel 2: one block per batch. 256 threads reduce split partials with high
// MLP; wave 0 lanes 0-31 run the 6 cell-A unfolds from pre-transformed LDS
// params, then cell B and the output sigmoid.
__global__ __launch_bounds__(256) void ltc_unfold(
    const float* __restrict__ pnum, const float* __restrict__ pden, int nsplit,
    const float* __restrict__ amu, const float* __restrict__ asig,
    const float* __restrict__ aW,  const float* __restrict__ aerev,
    const float* __restrict__ agleak, const float* __restrict__ avleak,
    const float* __restrict__ acm,
    const float* __restrict__ b_iw, const float* __restrict__ b_ib,
    const float* __restrict__ b_smu, const float* __restrict__ b_ssig,
    const float* __restrict__ b_sW,  const float* __restrict__ b_serev,
    const float* __restrict__ b_mu,  const float* __restrict__ b_sig,
    const float* __restrict__ b_W,   const float* __restrict__ b_erev,
    const float* __restrict__ b_gleak, const float* __restrict__ b_vleak,
    const float* __restrict__ b_cm,
    float* __restrict__ out)
{
    const int tid = threadIdx.x;
    const int b   = blockIdx.x;
    const int u   = tid & 31;
    const int sl  = tid >> 5;

    __shared__ float sred[8][NU][2];
    __shared__ float pAp[NU*NU], pCp[NU*NU];   // sig*log2e, mu*sig*log2e
    __shared__ float pW[NU*NU],  pWE[NU*NU];   // W, W*erev

    for (int p = tid; p < NU * NU; p += 256) {
        const float sg = asig[p] * LOG2E;
        pAp[p] = sg;
        pCp[p] = amu[p] * sg;
        const float w = aW[p];
        pW[p]  = w;
        pWE[p] = w * aerev[p];
    }

    float sn = 0.f, sd = 0.f;
    for (int s = sl; s < nsplit; s += 8) {
        const size_t gi = ((size_t)s * BATCH + b) * NU + u;
        sn += pnum[gi];
        sd += pden[gi];
    }
    sred[sl][u][0] = sn;
    sred[sl][u][1] = sd;
    __syncthreads();

    if (tid >= 32) return;

    float Sn = 0.f, Sd = 0.f;
#pragma unroll
    for (int s2 = 0; s2 < 8; ++s2) {
        Sn += sred[s2][u][0];
        Sd += sred[s2][u][1];
    }

    const float cmt = acm[u] * 6.0f;
    const float gl  = agleak[u];
    const float gv  = gl * avleak[u];

    float v = 0.f;
    for (int k = 0; k < 6; ++k) {
        float rn = 0.f, rd = 0.f;
#pragma unroll
        for (int j = 0; j < NU; ++j) {
            const float vj = __shfl(v, j, 32);
            const int pi = j * NU + u;
            const float e = __builtin_amdgcn_exp2f(pCp[pi] - vj * pAp[pi]);
            const float r = __builtin_amdgcn_rcpf(1.0f + e);   // sigmoid
            rn = fmaf(pWE[pi], r, rn);                         // += W*erev*sig
            rd = fmaf(pW[pi],  r, rd);                         // += W*sig
        }
        const float num = cmt * v + gv + rn + Sn;
        const float den = cmt + gl + rd + Sd;
        v = num / den;
    }

    const float x2 = v * b_iw[u] + b_ib[u];
    const float e2 = __builtin_amdgcn_exp2f((b_smu[u] - x2) * b_ssig[u] * LOG2E);
    const float s2v = b_sW[u] * __builtin_amdgcn_rcpf(1.0f + e2);
    float wn = s2v * b_serev[u];
    float wd = s2v;
#pragma unroll
    for (int m = 16; m >= 1; m >>= 1) {
        wn += __shfl_xor(wn, m, 32);
        wd += __shfl_xor(wd, m, 32);
    }

    const float bcmt = b_cm[0] * 6.0f;
    const float bgl  = b_gleak[0];
    const float bgv  = bgl * b_vleak[0];
    const float bmu  = b_mu[0], bsig = b_sig[0], bW = b_W[0], berev = b_erev[0];
    float v2 = 0.f;
#pragma unroll
    for (int k = 0; k < 6; ++k) {
        const float ee = __builtin_amdgcn_exp2f((bmu - v2) * bsig * LOG2E);
        const float ws = bW * __builtin_amdgcn_rcpf(1.0f + ee);
        const float num = bcmt * v2 + bgv + ws * berev + wn;
        const float den = bcmt + bgl + ws + wd;
        v2 = num / den;
    }

    if (u == 0)
        out[b] = 1.0f / (1.0f + __builtin_amdgcn_exp2f(-v2 * LOG2E));
}

extern "C" void kernel_launch(void* const* d_in, const int* in_sizes, int n_in,
                              void* d_out, int out_size, void* d_ws, size_t ws_size,
                              hipStream_t stream) {
    const float* x       = (const float*)d_in[0];
    const float* a_iw    = (const float*)d_in[1];
    const float* a_ib    = (const float*)d_in[2];
    const float* a_smu   = (const float*)d_in[3];
    const float* a_ssig  = (const float*)d_in[4];
    const float* a_sW    = (const float*)d_in[5];
    const float* a_serev = (const float*)d_in[6];
    const float* a_mu    = (const float*)d_in[7];
    const float* a_sig   = (const float*)d_in[8];
    const float* a_W     = (const float*)d_in[9];
    const float* a_erev  = (const float*)d_in[10];
    const float* a_gleak = (const float*)d_in[11];
    const float* a_vleak = (const float*)d_in[12];
    const float* a_cm    = (const float*)d_in[13];
    const float* b_iw    = (const float*)d_in[14];
    const float* b_ib    = (const float*)d_in[15];
    const float* b_smu   = (const float*)d_in[16];
    const float* b_ssig  = (const float*)d_in[17];
    const float* b_sW    = (const float*)d_in[18];
    const float* b_serev = (const float*)d_in[19];
    const float* b_mu    = (const float*)d_in[20];
    const float* b_sig   = (const float*)d_in[21];
    const float* b_W     = (const float*)d_in[22];
    const float* b_erev  = (const float*)d_in[23];
    const float* b_gleak = (const float*)d_in[24];
    const float* b_vleak = (const float*)d_in[25];
    const float* b_cm    = (const float*)d_in[26];
    float* out = (float*)d_out;

    int splits = 128;
    while (splits > 1 &&
           (size_t)splits * BATCH * NU * 2 * sizeof(float) > ws_size)
        splits >>= 1;
    int stripe = (IN1 + splits - 1) / splits;
    stripe = (stripe + 7) & ~7;
    const int gy = (IN1 + stripe - 1) / stripe;

    float* pnum = (float*)d_ws;
    float* pden = pnum + (size_t)splits * BATCH * NU;

    dim3 grid1(BGROUPS, gy);
    ltc_sensory_partial<<<grid1, 256, 0, stream>>>(
        x, a_iw, a_ib, a_smu, a_ssig, a_sW, a_serev, pnum, pden, stripe);

    ltc_unfold<<<BATCH, 256, 0, stream>>>(
        pnum, pden, gy,
        a_mu, a_sig, a_W, a_erev, a_gleak, a_vleak, a_cm,
        b_iw, b_ib, b_smu, b_ssig, b_sW, b_serev,
        b_mu, b_sig, b_W, b_erev, b_gleak, b_vleak, b_cm,
        out);
}

// Round 3
// 49.911 us; speedup vs baseline: 1.8813x; 1.0153x over previous
//
#include <hip/hip_runtime.h>

#define BATCH 256
#define IN1   10240
#define NU    32
#define NB    32
#define BGROUPS (BATCH / NB)
#define TILE_I 80
#define XPAD   84            // padded LDS row (floats), 16B-aligned rows
#define LOG2E 1.4426950408889634f

// ---------------- Kernel 1: sensory partial sums --------------------------
// block = (bg, is): 32 batches x one i-stripe. x tile staged in LDS; body
// reads x via ds_read broadcast with immediate offsets (no per-n addr math).
__global__ __launch_bounds__(256) void ltc_sensory_partial(
    const float* __restrict__ x,
    const float* __restrict__ iw, const float* __restrict__ ibias,
    const float* __restrict__ smu, const float* __restrict__ ssig,
    const float* __restrict__ sW, const float* __restrict__ serev,
    float2* __restrict__ part, int stripe)
{
    const int tid = threadIdx.x;
    const int u   = tid & 31;
    const int il  = tid >> 5;          // 0..7
    const int wv  = tid >> 6;          // 0..3
    const int b0  = blockIdx.x * NB;
    const int ibase = blockIdx.y * stripe;
    const int iend  = (ibase + stripe < IN1) ? (ibase + stripe) : IN1;

    union SmemT {
        float xL[NB][XPAD];            // 10.75 KB (live during body)
        float wred[4][NB][NU][2];      // 32 KB   (live after body)
    };
    __shared__ SmemT sm;

    float accn[NB], accd[NB];
#pragma unroll
    for (int n = 0; n < NB; ++n) { accn[n] = 0.f; accd[n] = 0.f; }

    const int lrow = tid >> 3;         // 0..31: row this thread helps load
    const int lq   = tid & 7;          // 0..7

    for (int cb = ibase; cb < iend; cb += TILE_I) {
        const int cend = (cb + TILE_I < iend) ? (cb + TILE_I) : iend;
        const int cw   = cend - cb;
        __syncthreads();               // previous tile fully consumed
        // stage x[b0..b0+31][cb..cend) -> sm.xL, float4 coalesced
        const float* xrow = x + (size_t)(b0 + lrow) * IN1 + cb;
        for (int c4 = lq; c4 * 4 < cw; c4 += 8) {
            if (c4 * 4 + 3 < cw) {
                const float4 v4 = *(const float4*)(xrow + c4 * 4);
                *(float4*)&sm.xL[lrow][c4 * 4] = v4;
            } else {
                for (int t = c4 * 4; t < cw; ++t)
                    sm.xL[lrow][t] = xrow[t];
            }
        }
        __syncthreads();

        for (int i = cb + il; i < cend; i += 8) {
            const int pi = i * NU + u;
            float A = ssig[pi] * LOG2E;
            const float C = (smu[pi] - ibias[i]) * A;
            A *= iw[i];
            const float sw  = sW[pi];
            const float swe = sw * serev[pi];
            const float* xr = &sm.xL[0][0] + (i - cb);   // + n*XPAD = imm offset
#pragma unroll
            for (int n = 0; n < NB; ++n) {
                const float xv = xr[n * XPAD];
                const float e  = __builtin_amdgcn_exp2f(C - xv * A);
                const float r  = __builtin_amdgcn_rcpf(1.0f + e);
                accd[n] = fmaf(sw,  r, accd[n]);
                accn[n] = fmaf(swe, r, accn[n]);
            }
        }
    }

    __syncthreads();                   // all xL reads done; reuse as wred
#pragma unroll
    for (int n = 0; n < NB; ++n) {
        float vn = accn[n] + __shfl_xor(accn[n], 32, 64);
        float vd = accd[n] + __shfl_xor(accd[n], 32, 64);
        if ((tid & 63) < 32) {
            sm.wred[wv][n][u][0] = vn;
            sm.wred[wv][n][u][1] = vd;
        }
    }
    __syncthreads();
    for (int p = tid; p < NB * NU; p += 256) {
        const int n = p >> 5, uu = p & 31;
        const float sn = sm.wred[0][n][uu][0] + sm.wred[1][n][uu][0]
                       + sm.wred[2][n][uu][0] + sm.wred[3][n][uu][0];
        const float sd = sm.wred[0][n][uu][1] + sm.wred[1][n][uu][1]
                       + sm.wred[2][n][uu][1] + sm.wred[3][n][uu][1];
        part[((size_t)blockIdx.y * BATCH + (b0 + n)) * NU + uu] =
            make_float2(sn, sd);
    }
}

// ---------------- Kernel 2: reduce split partials -------------------------
// one block per batch; thread (sl,u); float2 loads, fixed-order tree.
__global__ __launch_bounds__(256) void ltc_reduce(
    const float2* __restrict__ part, int nsplit, float2* __restrict__ S)
{
    const int tid = threadIdx.x;
    const int b   = blockIdx.x;
    const int u   = tid & 31;
    const int sl  = tid >> 5;

    __shared__ float sred[8][NU][2];

    float sn = 0.f, sd = 0.f;
#pragma unroll 4
    for (int s = sl; s < nsplit; s += 8) {
        const float2 p = part[((size_t)s * BATCH + b) * NU + u];
        sn += p.x;
        sd += p.y;
    }
    sred[sl][u][0] = sn;
    sred[sl][u][1] = sd;
    __syncthreads();

    if (tid >= 32) return;
    float Sn = 0.f, Sd = 0.f;
#pragma unroll
    for (int s2 = 0; s2 < 8; ++s2) {
        Sn += sred[s2][u][0];
        Sd += sred[s2][u][1];
    }
    S[(size_t)b * NU + u] = make_float2(Sn, Sd);
}

// ---------------- Kernel 3: unfolds + cell B + output ---------------------
// 32 blocks x 256 threads: 8 batches per block (one 32-lane group each).
__global__ __launch_bounds__(256) void ltc_unfold(
    const float2* __restrict__ S,
    const float* __restrict__ amu, const float* __restrict__ asig,
    const float* __restrict__ aW,  const float* __restrict__ aerev,
    const float* __restrict__ agleak, const float* __restrict__ avleak,
    const float* __restrict__ acm,
    const float* __restrict__ b_iw, const float* __restrict__ b_ib,
    const float* __restrict__ b_smu, const float* __restrict__ b_ssig,
    const float* __restrict__ b_sW,  const float* __restrict__ b_serev,
    const float* __restrict__ b_mu,  const float* __restrict__ b_sig,
    const float* __restrict__ b_W,   const float* __restrict__ b_erev,
    const float* __restrict__ b_gleak, const float* __restrict__ b_vleak,
    const float* __restrict__ b_cm,
    float* __restrict__ out)
{
    const int tid = threadIdx.x;
    const int u   = tid & 31;
    const int bl  = tid >> 5;                  // 0..7
    const int b   = blockIdx.x * 8 + bl;

    __shared__ float pAp[NU*NU], pCp[NU*NU];   // sig*log2e, mu*sig*log2e
    __shared__ float pW[NU*NU],  pWE[NU*NU];   // W, W*erev

    for (int p = tid; p < NU * NU; p += 256) {
        const float sg = asig[p] * LOG2E;
        pAp[p] = sg;
        pCp[p] = amu[p] * sg;
        const float w = aW[p];
        pW[p]  = w;
        pWE[p] = w * aerev[p];
    }
    __syncthreads();

    const float2 Sv = S[(size_t)b * NU + u];
    const float Sn = Sv.x, Sd = Sv.y;

    const float cmt = acm[u] * 6.0f;
    const float gl  = agleak[u];
    const float gv  = gl * avleak[u];

    float v = 0.f;
    for (int k = 0; k < 6; ++k) {
        float rn = 0.f, rd = 0.f;
#pragma unroll
        for (int j = 0; j < NU; ++j) {
            const float vj = __shfl(v, j, 32);
            const int pi = j * NU + u;
            const float e = __builtin_amdgcn_exp2f(pCp[pi] - vj * pAp[pi]);
            const float r = __builtin_amdgcn_rcpf(1.0f + e);
            rn = fmaf(pWE[pi], r, rn);
            rd = fmaf(pW[pi],  r, rd);
        }
        const float num = cmt * v + gv + rn + Sn;
        const float den = cmt + gl + rd + Sd;
        v = num / den;
    }

    const float x2  = v * b_iw[u] + b_ib[u];
    const float e2  = __builtin_amdgcn_exp2f((b_smu[u] - x2) * b_ssig[u] * LOG2E);
    const float s2v = b_sW[u] * __builtin_amdgcn_rcpf(1.0f + e2);
    float wn = s2v * b_serev[u];
    float wd = s2v;
#pragma unroll
    for (int m = 16; m >= 1; m >>= 1) {
        wn += __shfl_xor(wn, m, 32);
        wd += __shfl_xor(wd, m, 32);
    }

    const float bcmt = b_cm[0] * 6.0f;
    const float bgl  = b_gleak[0];
    const float bgv  = bgl * b_vleak[0];
    const float bmu  = b_mu[0], bsig = b_sig[0], bW = b_W[0], berev = b_erev[0];
    float v2 = 0.f;
#pragma unroll
    for (int k = 0; k < 6; ++k) {
        const float ee = __builtin_amdgcn_exp2f((bmu - v2) * bsig * LOG2E);
        const float ws = bW * __builtin_amdgcn_rcpf(1.0f + ee);
        const float num = bcmt * v2 + bgv + ws * berev + wn;
        const float den = bcmt + bgl + ws + wd;
        v2 = num / den;
    }

    if (u == 0)
        out[b] = 1.0f / (1.0f + __builtin_amdgcn_exp2f(-v2 * LOG2E));
}

extern "C" void kernel_launch(void* const* d_in, const int* in_sizes, int n_in,
                              void* d_out, int out_size, void* d_ws, size_t ws_size,
                              hipStream_t stream) {
    const float* x       = (const float*)d_in[0];
    const float* a_iw    = (const float*)d_in[1];
    const float* a_ib    = (const float*)d_in[2];
    const float* a_smu   = (const float*)d_in[3];
    const float* a_ssig  = (const float*)d_in[4];
    const float* a_sW    = (const float*)d_in[5];
    const float* a_serev = (const float*)d_in[6];
    const float* a_mu    = (const float*)d_in[7];
    const float* a_sig   = (const float*)d_in[8];
    const float* a_W     = (const float*)d_in[9];
    const float* a_erev  = (const float*)d_in[10];
    const float* a_gleak = (const float*)d_in[11];
    const float* a_vleak = (const float*)d_in[12];
    const float* a_cm    = (const float*)d_in[13];
    const float* b_iw    = (const float*)d_in[14];
    const float* b_ib    = (const float*)d_in[15];
    const float* b_smu   = (const float*)d_in[16];
    const float* b_ssig  = (const float*)d_in[17];
    const float* b_sW    = (const float*)d_in[18];
    const float* b_serev = (const float*)d_in[19];
    const float* b_mu    = (const float*)d_in[20];
    const float* b_sig   = (const float*)d_in[21];
    const float* b_W     = (const float*)d_in[22];
    const float* b_erev  = (const float*)d_in[23];
    const float* b_gleak = (const float*)d_in[24];
    const float* b_vleak = (const float*)d_in[25];
    const float* b_cm    = (const float*)d_in[26];
    float* out = (float*)d_out;

    int splits = 128;
    while (splits > 1 &&
           ((size_t)splits * BATCH * NU + BATCH * NU) * sizeof(float2) > ws_size)
        splits >>= 1;
    int stripe = (IN1 + splits - 1) / splits;
    stripe = (stripe + 7) & ~7;
    const int gy = (IN1 + stripe - 1) / stripe;

    float2* part = (float2*)d_ws;
    float2* S    = part + (size_t)splits * BATCH * NU;

    dim3 grid1(BGROUPS, gy);
    ltc_sensory_partial<<<grid1, 256, 0, stream>>>(
        x, a_iw, a_ib, a_smu, a_ssig, a_sW, a_serev, part, stripe);

    ltc_reduce<<<BATCH, 256, 0, stream>>>(part, gy, S);

    ltc_unfold<<<BATCH / 8, 256, 0, stream>>>(
        S,
        a_mu, a_sig, a_W, a_erev, a_gleak, a_vleak, a_cm,
        b_iw, b_ib, b_smu, b_ssig, b_sW, b_serev,
        b_mu, b_sig, b_W, b_erev, b_gleak, b_vleak, b_cm,
        out);
}

// Round 4
// 45.079 us; speedup vs baseline: 2.0829x; 1.1072x over previous
//
#include <hip/hip_runtime.h>

#define BATCH 256
#define IN1   10240
#define NU    32
#define NB    32              // batches per block
#define BGROUPS (BATCH / NB)  // 8
#define CHUNK 40              // i-chunk staged in LDS (divides 10240)
#define XPAD  44              // padded LDS x row (floats)
#define LOG2E 1.4426950408889634f

// ---------------- Kernel 1: sensory partial sums --------------------------
// block = (bg, is). thread = (u = tid&31, g = tid>>5); thread owns batches
// n = 4g..4g+3 over the whole stripe -> 8 acc VGPRs, no cross-thread reduce.
// Per chunk: params transformed once into LDS float4 {A, C, sW, sW*serev};
// x tile staged in LDS. Body: ds broadcast reads + fma/exp2/add/rcp/2fma.
__global__ __launch_bounds__(256) void ltc_sensory_partial(
    const float* __restrict__ x,
    const float* __restrict__ iw, const float* __restrict__ ibias,
    const float* __restrict__ smu, const float* __restrict__ ssig,
    const float* __restrict__ sW, const float* __restrict__ serev,
    float2* __restrict__ part, int stripe)
{
    const int tid = threadIdx.x;
    const int u   = tid & 31;
    const int g   = tid >> 5;          // 0..7, owns n = 4g..4g+3
    const int b0  = blockIdx.x * NB;
    const int ibase = blockIdx.y * stripe;
    const int iend  = ibase + stripe;  // stripe divides IN1 exactly

    __shared__ float4 sP[CHUNK * NU];  // 20480 B: {A, C, sW, sW*serev}
    __shared__ float  xL[NB][XPAD];    //  5632 B

    float accn[4], accd[4];
#pragma unroll
    for (int k = 0; k < 4; ++k) { accn[k] = 0.f; accd[k] = 0.f; }

    const int lrow = tid >> 3;         // x-staging: row 0..31
    const int lq   = tid & 7;          // 8 threads per row

    for (int cb = ibase; cb < iend; cb += CHUNK) {
        __syncthreads();               // previous chunk fully consumed

        // stage transformed params: 1280 elems / 256 threads = 5 iters
#pragma unroll
        for (int p = tid; p < CHUNK * NU; p += 256) {
            const int ii = cb + (p >> 5);
            const int gi = ii * NU + (p & 31);
            const float sg = ssig[gi] * LOG2E;
            const float w  = sW[gi];
            sP[p] = make_float4(sg * iw[ii],
                                (smu[gi] - ibias[ii]) * sg,
                                w, w * serev[gi]);
        }
        // stage x[b0+row][cb..cb+40): 10 float4 per row, 8 threads/row
        const float* xrow = x + (size_t)(b0 + lrow) * IN1 + cb;
        {
            const float4 v4 = *(const float4*)(xrow + lq * 4);
            *(float4*)&xL[lrow][lq * 4] = v4;
            if (lq < 2) {
                const float4 w4 = *(const float4*)(xrow + (lq + 8) * 4);
                *(float4*)&xL[lrow][(lq + 8) * 4] = w4;
            }
        }
        __syncthreads();

        const float* xr = &xL[g * 4][0];
#pragma unroll 2
        for (int di = 0; di < CHUNK; ++di) {
            const float4 f = sP[di * NU + u];   // broadcast per half-wave
#pragma unroll
            for (int k = 0; k < 4; ++k) {
                const float xv = xr[k * XPAD + di];
                const float e  = __builtin_amdgcn_exp2f(f.y - xv * f.x);
                const float r  = __builtin_amdgcn_rcpf(1.0f + e);
                accd[k] = fmaf(f.z, r, accd[k]);
                accn[k] = fmaf(f.w, r, accn[k]);
            }
        }
    }

    // direct write: thread owns (b0+4g+k, u)
#pragma unroll
    for (int k = 0; k < 4; ++k) {
        part[((size_t)blockIdx.y * BATCH + (b0 + g * 4 + k)) * NU + u] =
            make_float2(accn[k], accd[k]);
    }
}

// ---------------- Kernel 2: reduce split partials -------------------------
__global__ __launch_bounds__(256) void ltc_reduce(
    const float2* __restrict__ part, int nsplit, float2* __restrict__ S)
{
    const int tid = threadIdx.x;
    const int b   = blockIdx.x;
    const int u   = tid & 31;
    const int sl  = tid >> 5;

    __shared__ float sred[8][NU][2];

    float sn = 0.f, sd = 0.f;
#pragma unroll 8
    for (int s = sl; s < nsplit; s += 8) {
        const float2 p = part[((size_t)s * BATCH + b) * NU + u];
        sn += p.x;
        sd += p.y;
    }
    sred[sl][u][0] = sn;
    sred[sl][u][1] = sd;
    __syncthreads();

    if (tid >= 32) return;
    float Sn = 0.f, Sd = 0.f;
#pragma unroll
    for (int s2 = 0; s2 < 8; ++s2) {
        Sn += sred[s2][u][0];
        Sd += sred[s2][u][1];
    }
    S[(size_t)b * NU + u] = make_float2(Sn, Sd);
}

// ---------------- Kernel 3: unfolds + cell B + output ---------------------
__global__ __launch_bounds__(256) void ltc_unfold(
    const float2* __restrict__ S,
    const float* __restrict__ amu, const float* __restrict__ asig,
    const float* __restrict__ aW,  const float* __restrict__ aerev,
    const float* __restrict__ agleak, const float* __restrict__ avleak,
    const float* __restrict__ acm,
    const float* __restrict__ b_iw, const float* __restrict__ b_ib,
    const float* __restrict__ b_smu, const float* __restrict__ b_ssig,
    const float* __restrict__ b_sW,  const float* __restrict__ b_serev,
    const float* __restrict__ b_mu,  const float* __restrict__ b_sig,
    const float* __restrict__ b_W,   const float* __restrict__ b_erev,
    const float* __restrict__ b_gleak, const float* __restrict__ b_vleak,
    const float* __restrict__ b_cm,
    float* __restrict__ out)
{
    const int tid = threadIdx.x;
    const int u   = tid & 31;
    const int bl  = tid >> 5;
    const int b   = blockIdx.x * 8 + bl;

    __shared__ float pAp[NU*NU], pCp[NU*NU];
    __shared__ float pW[NU*NU],  pWE[NU*NU];

    for (int p = tid; p < NU * NU; p += 256) {
        const float sg = asig[p] * LOG2E;
        pAp[p] = sg;
        pCp[p] = amu[p] * sg;
        const float w = aW[p];
        pW[p]  = w;
        pWE[p] = w * aerev[p];
    }
    __syncthreads();

    const float2 Sv = S[(size_t)b * NU + u];
    const float Sn = Sv.x, Sd = Sv.y;

    const float cmt = acm[u] * 6.0f;
    const float gl  = agleak[u];
    const float gv  = gl * avleak[u];

    float v = 0.f;
    for (int k = 0; k < 6; ++k) {
        float rn = 0.f, rd = 0.f;
#pragma unroll
        for (int j = 0; j < NU; ++j) {
            const float vj = __shfl(v, j, 32);
            const int pi = j * NU + u;
            const float e = __builtin_amdgcn_exp2f(pCp[pi] - vj * pAp[pi]);
            const float r = __builtin_amdgcn_rcpf(1.0f + e);
            rn = fmaf(pWE[pi], r, rn);
            rd = fmaf(pW[pi],  r, rd);
        }
        const float num = cmt * v + gv + rn + Sn;
        const float den = cmt + gl + rd + Sd;
        v = num / den;
    }

    const float x2  = v * b_iw[u] + b_ib[u];
    const float e2  = __builtin_amdgcn_exp2f((b_smu[u] - x2) * b_ssig[u] * LOG2E);
    const float s2v = b_sW[u] * __builtin_amdgcn_rcpf(1.0f + e2);
    float wn = s2v * b_serev[u];
    float wd = s2v;
#pragma unroll
    for (int m = 16; m >= 1; m >>= 1) {
        wn += __shfl_xor(wn, m, 32);
        wd += __shfl_xor(wd, m, 32);
    }

    const float bcmt = b_cm[0] * 6.0f;
    const float bgl  = b_gleak[0];
    const float bgv  = bgl * b_vleak[0];
    const float bmu  = b_mu[0], bsig = b_sig[0], bW = b_W[0], berev = b_erev[0];
    float v2 = 0.f;
#pragma unroll
    for (int k = 0; k < 6; ++k) {
        const float ee = __builtin_amdgcn_exp2f((bmu - v2) * bsig * LOG2E);
        const float ws = bW * __builtin_amdgcn_rcpf(1.0f + ee);
        const float num = bcmt * v2 + bgv + ws * berev + wn;
        const float den = bcmt + bgl + ws + wd;
        v2 = num / den;
    }

    if (u == 0)
        out[b] = 1.0f / (1.0f + __builtin_amdgcn_exp2f(-v2 * LOG2E));
}

extern "C" void kernel_launch(void* const* d_in, const int* in_sizes, int n_in,
                              void* d_out, int out_size, void* d_ws, size_t ws_size,
                              hipStream_t stream) {
    const float* x       = (const float*)d_in[0];
    const float* a_iw    = (const float*)d_in[1];
    const float* a_ib    = (const float*)d_in[2];
    const float* a_smu   = (const float*)d_in[3];
    const float* a_ssig  = (const float*)d_in[4];
    const float* a_sW    = (const float*)d_in[5];
    const float* a_serev = (const float*)d_in[6];
    const float* a_mu    = (const float*)d_in[7];
    const float* a_sig   = (const float*)d_in[8];
    const float* a_W     = (const float*)d_in[9];
    const float* a_erev  = (const float*)d_in[10];
    const float* a_gleak = (const float*)d_in[11];
    const float* a_vleak = (const float*)d_in[12];
    const float* a_cm    = (const float*)d_in[13];
    const float* b_iw    = (const float*)d_in[14];
    const float* b_ib    = (const float*)d_in[15];
    const float* b_smu   = (const float*)d_in[16];
    const float* b_ssig  = (const float*)d_in[17];
    const float* b_sW    = (const float*)d_in[18];
    const float* b_serev = (const float*)d_in[19];
    const float* b_mu    = (const float*)d_in[20];
    const float* b_sig   = (const float*)d_in[21];
    const float* b_W     = (const float*)d_in[22];
    const float* b_erev  = (const float*)d_in[23];
    const float* b_gleak = (const float*)d_in[24];
    const float* b_vleak = (const float*)d_in[25];
    const float* b_cm    = (const float*)d_in[26];
    float* out = (float*)d_out;

    // splits: power of two so stripe = IN1/splits is a multiple of CHUNK=40
    int splits = 256;
    while (splits > 4 &&
           ((size_t)splits * BATCH * NU + BATCH * NU) * sizeof(float2) > ws_size)
        splits >>= 1;
    const int stripe = IN1 / splits;

    float2* part = (float2*)d_ws;
    float2* S    = part + (size_t)splits * BATCH * NU;

    dim3 grid1(BGROUPS, splits);
    ltc_sensory_partial<<<grid1, 256, 0, stream>>>(
        x, a_iw, a_ib, a_smu, a_ssig, a_sW, a_serev, part, stripe);

    ltc_reduce<<<BATCH, 256, 0, stream>>>(part, splits, S);

    ltc_unfold<<<BATCH / 8, 256, 0, stream>>>(
        S,
        a_mu, a_sig, a_W, a_erev, a_gleak, a_vleak, a_cm,
        b_iw, b_ib, b_smu, b_ssig, b_sW, b_serev,
        b_mu, b_sig, b_W, b_erev, b_gleak, b_vleak, b_cm,
        out);
}